// Round 1
// baseline (132.734 us; speedup 1.0000x reference)
//
#include <hip/hip_runtime.h>
#include <hip/hip_fp16.h>

#define NTOT 8192
#define NHALF 4096
#define DIM 256
#define LOG2E 1.4426950408889634f
#define NEG_BIG -1e30f
#define COLSPLIT 8
#define BM 128
#define BN 64
#define CPB (NTOT / COLSPLIT) /* 1024 cols per block */

typedef _Float16 half8 __attribute__((ext_vector_type(8)));
typedef float floatx4 __attribute__((ext_vector_type(4)));

// ---------------- normalize: z1|z2 -> fp16 row-normalized zn ----------------
__global__ __launch_bounds__(256) void k_normalize(const float* __restrict__ z1,
                                                   const float* __restrict__ z2,
                                                   __half* __restrict__ zn) {
  int row = blockIdx.x * 4 + (threadIdx.x >> 6);
  int lane = threadIdx.x & 63;
  const float* src = (row < NHALF) ? (z1 + (size_t)row * DIM)
                                   : (z2 + (size_t)(row - NHALF) * DIM);
  float4 v = ((const float4*)src)[lane];
  float ss = v.x * v.x + v.y * v.y + v.z * v.z + v.w * v.w;
#pragma unroll
  for (int m = 1; m < 64; m <<= 1) ss += __shfl_xor(ss, m);
  float inv = 1.0f / fmaxf(sqrtf(ss), 1e-8f);
  __half2 h0, h1;
  h0.x = __float2half_rn(v.x * inv);
  h0.y = __float2half_rn(v.y * inv);
  h1.x = __float2half_rn(v.z * inv);
  h1.y = __float2half_rn(v.w * inv);
  __half2* dst = (__half2*)(zn + (size_t)row * DIM + lane * 4);
  dst[0] = h0;
  dst[1] = h1;
}

// ---------------- target similarities: t_i = zn_i . zn_{i+-N} ----------------
__global__ __launch_bounds__(256) void k_tsim(const __half* __restrict__ zn,
                                              float* __restrict__ tsim) {
  int row = blockIdx.x * 4 + (threadIdx.x >> 6);
  int lane = threadIdx.x & 63;
  int tgt = (row < NHALF) ? row + NHALF : row - NHALF;
  const __half2* a = (const __half2*)(zn + (size_t)row * DIM);
  const __half2* b = (const __half2*)(zn + (size_t)tgt * DIM);
  float s = 0.f;
#pragma unroll
  for (int j = 0; j < 2; j++) {
    float2 xf = __half22float2(a[lane * 2 + j]);
    float2 yf = __half22float2(b[lane * 2 + j]);
    s += xf.x * yf.x + xf.y * yf.y;
  }
#pragma unroll
  for (int m = 1; m < 64; m <<= 1) s += __shfl_xor(s, m);
  if (lane == 0) tsim[row] = s;
}

// ---------------- main fused S-pass: online softmax + argmax ----------------
// grid = 64 rowTiles x 8 colSplits = 512 blocks, 256 threads (4 waves x 32 rows)
__global__ __launch_bounds__(256, 2) void k_main(const __half* __restrict__ zn,
                                                 const float* __restrict__ logT,
                                                 float* __restrict__ pM,
                                                 float* __restrict__ pL,
                                                 int* __restrict__ pI) {
  __shared__ uint4 lds[BN * 32];  // 64 rows x 32 x 16B = 32 KB, xor-swizzled

  int bx = blockIdx.x;
  int rowTile = bx >> 3;
  int colq = bx & 7;
  int rowBase = rowTile * BM;
  int colBase = colq * CPB;
  int tid = threadIdx.x;
  int w = tid >> 6;
  int lane = tid & 63;
  int quad = lane >> 4;
  int cl = lane & 15;

  float invT = expf(-logT[0]);
  float kk = invT * LOG2E;

  // A fragments in registers: wave owns rows [rowBase+w*32, +32), 2 tiles of 16
  half8 a[2][8];
  {
    int ar0 = rowBase + w * 32 + cl;
    int ar1 = ar0 + 16;
#pragma unroll
    for (int ks = 0; ks < 8; ks++) {
      a[0][ks] = *(const half8*)(zn + (size_t)ar0 * DIM + ks * 32 + quad * 8);
      a[1][ks] = *(const half8*)(zn + (size_t)ar1 * DIM + ks * 32 + quad * 8);
    }
  }

  // per-lane online softmax state; lane covers cols == cl (mod 16) of its rows
  float M[8], L[8];
  int AI[8];
#pragma unroll
  for (int s = 0; s < 8; s++) {
    M[s] = -3e38f;
    L[s] = 0.f;
    AI[s] = 0;
  }

  for (int t = 0; t < CPB / BN; t++) {  // 16 column tiles of 64
    __syncthreads();
    // stage B tile: 64 rows x 512B, xor-swizzle chunk index to break bank conflicts
#pragma unroll
    for (int i = 0; i < 8; i++) {
      int idx = tid + i * 256;
      int c = idx >> 5, ch = idx & 31;
      int g = colBase + t * BN + c;
      uint4 v = *(const uint4*)(zn + (size_t)g * DIM + ch * 8);
      lds[c * 32 + (ch ^ (c & 7))] = v;
    }
    __syncthreads();

    floatx4 acc[2][4];
#pragma unroll
    for (int rt = 0; rt < 2; rt++)
#pragma unroll
      for (int nt = 0; nt < 4; nt++) acc[rt][nt] = (floatx4){0.f, 0.f, 0.f, 0.f};

#pragma unroll
    for (int nt = 0; nt < 4; nt++) {
      int bc = nt * 16 + cl;
#pragma unroll
      for (int ks = 0; ks < 8; ks++) {
        int ch = ks * 4 + quad;
        half8 b = *(const half8*)&lds[bc * 32 + (ch ^ (bc & 7))];
        acc[0][nt] = __builtin_amdgcn_mfma_f32_16x16x32_f16(a[0][ks], b, acc[0][nt], 0, 0, 0);
        acc[1][nt] = __builtin_amdgcn_mfma_f32_16x16x32_f16(a[1][ks], b, acc[1][nt], 0, 0, 0);
      }
    }

    // per-lane online update (no cross-lane traffic in hot loop)
    int colT = colBase + t * BN;
#pragma unroll
    for (int rt = 0; rt < 2; rt++) {
      int growB = rowBase + w * 32 + rt * 16 + quad * 4;
#pragma unroll
      for (int r = 0; r < 4; r++) {
        int grow = growB + r;
        float v0 = acc[rt][0][r], v1 = acc[rt][1][r];
        float v2 = acc[rt][2][r], v3 = acc[rt][3][r];
        int c0 = colT + cl;
        if (c0 == grow) v0 = NEG_BIG;
        if (c0 + 16 == grow) v1 = NEG_BIG;
        if (c0 + 32 == grow) v2 = NEG_BIG;
        if (c0 + 48 == grow) v3 = NEG_BIG;
        float mv = v0;
        int mi = c0;
        if (v1 > mv) { mv = v1; mi = c0 + 16; }
        if (v2 > mv) { mv = v2; mi = c0 + 32; }
        if (v3 > mv) { mv = v3; mi = c0 + 48; }
        int slot = rt * 4 + r;
        float Mo = M[slot];
        float Mn = fmaxf(Mo, mv);
        if (mv > Mo) AI[slot] = mi;  // strict >: first occurrence wins (cols ascend)
        float se = exp2f((v0 - Mn) * kk) + exp2f((v1 - Mn) * kk) +
                   exp2f((v2 - Mn) * kk) + exp2f((v3 - Mn) * kk);
        L[slot] = L[slot] * exp2f((Mo - Mn) * kk) + se;
        M[slot] = Mn;
      }
    }
  }

  // combine the 16 per-lane partials within each quad (rows are per-quad)
#pragma unroll
  for (int s = 0; s < 8; s++) {
    float m = M[s], l = L[s];
    int ai = AI[s];
#pragma unroll
    for (int sh = 1; sh < 16; sh <<= 1) {
      float om = __shfl_xor(m, sh);
      float ol = __shfl_xor(l, sh);
      int oi = __shfl_xor(ai, sh);
      float mn = fmaxf(m, om);
      l = l * exp2f((m - mn) * kk) + ol * exp2f((om - mn) * kk);
      if (om > m || (om == m && oi < ai)) ai = oi;
      m = mn;
    }
    M[s] = m;
    L[s] = l;
    AI[s] = ai;
  }

  if (cl == 0) {
#pragma unroll
    for (int rt = 0; rt < 2; rt++)
#pragma unroll
      for (int r = 0; r < 4; r++) {
        int grow = rowBase + w * 32 + rt * 16 + quad * 4 + r;
        int s = rt * 4 + r;
        int p = grow * COLSPLIT + colq;
        pM[p] = M[s];
        pL[p] = L[s];
        pI[p] = AI[s];
      }
  }
}

// ---------------- final reduce: combine col-splits, loss + correct ----------------
__global__ __launch_bounds__(256) void k_reduce(const float* __restrict__ pM,
                                                const float* __restrict__ pL,
                                                const int* __restrict__ pI,
                                                const float* __restrict__ tsim,
                                                const float* __restrict__ logT,
                                                float* __restrict__ out) {
  int row = blockIdx.x * 256 + threadIdx.x;  // grid 32 -> 8192 rows
  float invT = expf(-logT[0]);
  float kk = invT * LOG2E;
  float m = -3e38f;
  int idx = 0;
#pragma unroll
  for (int q = 0; q < COLSPLIT; q++) {
    float mq = pM[row * COLSPLIT + q];
    if (mq > m) { m = mq; idx = pI[row * COLSPLIT + q]; }
  }
  float Lt = 0.f;
#pragma unroll
  for (int q = 0; q < COLSPLIT; q++)
    Lt += pL[row * COLSPLIT + q] * exp2f((pM[row * COLSPLIT + q] - m) * kk);
  int tgt = (row < NHALF) ? row + NHALF : row - NHALF;
  float logpt = (tsim[row] - m) * invT - logf(Lt);
  float loss = -logpt;
  float corr = (idx == tgt) ? 1.f : 0.f;

  __shared__ float sl[256], sc[256];
  sl[threadIdx.x] = loss;
  sc[threadIdx.x] = corr;
  __syncthreads();
  for (int s = 128; s > 0; s >>= 1) {
    if (threadIdx.x < s) {
      sl[threadIdx.x] += sl[threadIdx.x + s];
      sc[threadIdx.x] += sc[threadIdx.x + s];
    }
    __syncthreads();
  }
  if (threadIdx.x == 0) {
    atomicAdd(out + 0, sl[0] * (1.0f / (float)NTOT));
    atomicAdd(out + 1, sc[0] * 0.5f);
  }
}

extern "C" void kernel_launch(void* const* d_in, const int* in_sizes, int n_in,
                              void* d_out, int out_size, void* d_ws, size_t ws_size,
                              hipStream_t stream) {
  const float* z1 = (const float*)d_in[0];
  const float* z2 = (const float*)d_in[1];
  const float* logT = (const float*)d_in[2];
  float* out = (float*)d_out;

  // workspace layout
  char* ws = (char*)d_ws;
  __half* zn = (__half*)ws;                                   // 8192*256*2 = 4 MB
  float* tsim = (float*)(ws + 4 * 1024 * 1024);               // 32 KB
  float* pM = (float*)(ws + 4 * 1024 * 1024 + 32 * 1024);     // 256 KB
  float* pL = (float*)((char*)pM + NTOT * COLSPLIT * 4);      // 256 KB
  int* pI = (int*)((char*)pL + NTOT * COLSPLIT * 4);          // 256 KB

  k_normalize<<<NTOT / 4, 256, 0, stream>>>(z1, z2, zn);
  k_tsim<<<NTOT / 4, 256, 0, stream>>>(zn, tsim);
  k_main<<<(NTOT / BM) * COLSPLIT, 256, 0, stream>>>(zn, logT, pM, pL, pI);
  hipMemsetAsync(d_out, 0, 2 * sizeof(float), stream);
  k_reduce<<<NTOT / 256, 256, 0, stream>>>(pM, pL, pI, tsim, logT, out);
}